// Round 1
// baseline (28260.614 us; speedup 1.0000x reference)
//
#include <hip/hip_runtime.h>

// ---- problem constants ----
#define RPB 4            // batch rows per block
// ws layout (float offsets)
#define WS_WCAT   0                       // [384][1024] gates weights, col = u*4+q
#define WS_LINT   (WS_WCAT + 384*1024)    // [160][1024] lin_W, col = s*8+n
#define WS_BZ     (WS_LINT + 160*1024)    // [1024] combined wlstm bias, col layout
#define WS_LINB   (WS_BZ + 1024)          // [1024] lin_b, col = s*8+n
#define WS_MU0    (WS_LINB + 1024)        // [128]
#define WS_SEXP   (WS_MU0 + 128)          // [128] exp(0.5*ls0)
#define WS_RNNT   (WS_SEXP + 128)         // [512][1024] rnn weights, col = u*4+q
#define WS_BRNN   (WS_RNNT + 512*1024)    // [1024]
#define WS_PPT1   (WS_BRNN + 1024)        // [96][256]
#define WS_PPT2   (WS_PPT1 + 96*256)      // [256][256]

// out offsets (return order, flat)
#define OUT_OBS_MU 0
#define OUT_OBS_S  (256*1024*64)
#define OUT_HPOST  (2*256*1024*64)
#define OUT_CPOST  (OUT_HPOST + 1024*256)
#define OUT_WH     (OUT_CPOST + 1024*256)
#define OUT_WC     (OUT_WH + 1024*256)
#define OUT_WMAP   (OUT_WC + 1024*256)

__device__ __forceinline__ float sigm(float x){ return 1.0f/(1.0f+__expf(-x)); }
// overflow-safe tanh: large +x -> 1, large -x -> 2/(1+inf)-1 = -1
__device__ __forceinline__ float tanhf_fast(float x){ return 2.0f/(1.0f+__expf(-2.0f*x)) - 1.0f; }

// ---------------- prep kernels (run every call; cheap) ----------------
__global__ void prep_wcat(const float* __restrict__ Wih, const float* __restrict__ Whh,
                          float* __restrict__ ws){
    int idx = blockIdx.x*256 + threadIdx.x;          // < 384*1024
    int i = idx >> 10, col = idx & 1023;
    int u = col >> 2, q = col & 3;                   // PyTorch gate order i,f,g,o
    float v = (i < 128) ? Wih[(q*256+u)*128 + i] : Whh[(q*256+u)*256 + (i-128)];
    ws[WS_WCAT + idx] = v;
}
__global__ void prep_lin(const float* __restrict__ lin_W, float* __restrict__ ws){
    int idx = blockIdx.x*256 + threadIdx.x;          // < 160*1024
    int i = idx >> 10, col = idx & 1023;
    int s = col >> 3, n = col & 7;
    ws[WS_LINT + idx] = lin_W[(n*128 + s)*160 + i];
}
__global__ void prep_rnn(const float* __restrict__ Wih, const float* __restrict__ Whh,
                         float* __restrict__ ws){
    int idx = blockIdx.x*256 + threadIdx.x;          // < 512*1024
    int i = idx >> 10, col = idx & 1023;
    int u = col >> 2, q = col & 3;
    float v = (i < 256) ? Wih[(q*256+u)*256 + i] : Whh[(q*256+u)*256 + (i-256)];
    ws[WS_RNNT + idx] = v;
}
__global__ void prep_bias(const float* __restrict__ wbih, const float* __restrict__ wbhh,
                          const float* __restrict__ rbih, const float* __restrict__ rbhh,
                          const float* __restrict__ lin_b, float* __restrict__ ws){
    int idx = blockIdx.x*256 + threadIdx.x;          // < 1024
    int u = idx >> 2, q = idx & 3;
    ws[WS_BZ + idx]   = wbih[q*256+u] + wbhh[q*256+u];
    ws[WS_BRNN + idx] = rbih[q*256+u] + rbhh[q*256+u];
    int s = idx >> 3, n = idx & 7;
    ws[WS_LINB + idx] = lin_b[n*128 + s];
}
__global__ void prep_pp(const float* __restrict__ W1, const float* __restrict__ W2,
                        float* __restrict__ ws){
    int idx = blockIdx.x*256 + threadIdx.x;          // < 96*256 + 256*256
    if (idx < 96*256){
        int i = idx >> 8, j = idx & 255;
        ws[WS_PPT1 + idx] = W1[j*96 + i];
    } else {
        int k = idx - 96*256;
        int i = k >> 8, j = k & 255;
        ws[WS_PPT2 + k] = W2[j*256 + i];
    }
}
// initial DBlock on the single broadcast h0 row
__global__ void dblock0(const float* __restrict__ h0,
                        const float* __restrict__ W1, const float* __restrict__ b1,
                        const float* __restrict__ W2, const float* __restrict__ b2,
                        const float* __restrict__ Wmu, const float* __restrict__ bmu,
                        const float* __restrict__ Wls, const float* __restrict__ bls,
                        float* __restrict__ ws){
    __shared__ float s_t[512];
    __shared__ float s_h[256];
    int tid = threadIdx.x;                            // 512 threads
    if (tid < 256) s_h[tid] = h0[tid];
    __syncthreads();
    {
        float a = b1[tid], b = b2[tid];
        for (int i=0;i<256;i++){ float h = s_h[i]; a += h*W1[tid*256+i]; b += h*W2[tid*256+i]; }
        s_t[tid] = tanhf_fast(a)*sigm(b);
    }
    __syncthreads();
    if (tid < 128){
        float m = bmu[tid];
        for (int k=0;k<512;k++) m += s_t[k]*Wmu[tid*512+k];
        ws[WS_MU0 + tid] = m;
    } else if (tid < 256){
        int j = tid - 128;
        float l = bls[j];
        for (int k=0;k<512;k++) l += s_t[k]*Wls[j*512+k];
        ws[WS_SEXP + j] = __expf(0.5f*l);
    }
}

// ---------------- scan 1: weight-LSTM + combinational linears + emission ----------------
__global__ __launch_bounds__(256) void scan1_kernel(
    const float* __restrict__ ext, const float* __restrict__ eps_init,
    const float* __restrict__ eps_seq, const float* __restrict__ eps_obs,
    const float* __restrict__ dyn_h0,
    const float* __restrict__ wl_W, const float* __restrict__ wl_b,
    const float* __restrict__ dyn_logsigma,
    const float* __restrict__ est_logdelta, const float* __restrict__ est_H,
    const float* __restrict__ est_b,
    const float* __restrict__ ws, float* __restrict__ out)
{
    const int tid = threadIdx.x;
    const int r0  = blockIdx.x * RPB;

    __shared__ __align__(16) float s_x[RPB][384];   // [state(128) | wh(256)]
    __shared__ __align__(16) float s_xc[RPB][160];  // [state(128) | u(32)]
    __shared__ float s_w[RPB][8];
    __shared__ float s_wlog[RPB][8];
    __shared__ float s_HT[128][64];                 // H transposed [s][o]
    __shared__ float s_dstd[128];
    __shared__ float s_ostd[64];
    __shared__ float s_eb[64];

    for (int idx = tid; idx < 128*64; idx += 256){
        int s = idx >> 6, o = idx & 63;
        s_HT[s][o] = est_H[o*128 + s];
    }
    if (tid < 128) s_dstd[tid] = __expf(0.5f*dyn_logsigma[tid]);
    if (tid < 64){ s_ostd[tid] = __expf(0.5f*est_logdelta[tid]); s_eb[tid] = est_b[tid]; }

    if (tid < 128){
        float m = ws[WS_MU0+tid], sd = ws[WS_SEXP+tid];
        #pragma unroll
        for (int r=0;r<RPB;r++){
            float v = m + sd*eps_init[(r0+r)*128 + tid];
            s_x[r][tid] = v; s_xc[r][tid] = v;
        }
    }
    {
        float h0v = dyn_h0[tid];
        #pragma unroll
        for (int r=0;r<RPB;r++) s_x[r][128+tid] = h0v;
    }
    float c_reg[RPB];
    #pragma unroll
    for (int r=0;r<RPB;r++) c_reg[r] = 0.0f;

    const float4* Wc4 = ((const float4*)(ws + WS_WCAT)) + tid;   // col group 4*tid = unit tid gates i,f,g,o
    const float4* Ln4 = ((const float4*)(ws + WS_LINT)) + tid;
    const float4  bz4 = ((const float4*)(ws + WS_BZ))[tid];
    const float4  lb4 = ((const float4*)(ws + WS_LINB))[tid];

    __syncthreads();

    for (int t = 0; t < 256; t++){
        // gates GEMV over [state|h] (K=384)
        float ac[RPB][4];
        #pragma unroll
        for (int r=0;r<RPB;r++){ ac[r][0]=bz4.x; ac[r][1]=bz4.y; ac[r][2]=bz4.z; ac[r][3]=bz4.w; }
        for (int i4=0;i4<96;i4++){
            float4 w0 = Wc4[(4*i4+0)*256];
            float4 w1 = Wc4[(4*i4+1)*256];
            float4 w2 = Wc4[(4*i4+2)*256];
            float4 w3 = Wc4[(4*i4+3)*256];
            #pragma unroll
            for (int r=0;r<RPB;r++){
                float4 xv = ((const float4*)s_x[r])[i4];
                ac[r][0] += xv.x*w0.x + xv.y*w1.x + xv.z*w2.x + xv.w*w3.x;
                ac[r][1] += xv.x*w0.y + xv.y*w1.y + xv.z*w2.y + xv.w*w3.y;
                ac[r][2] += xv.x*w0.z + xv.y*w1.z + xv.z*w2.z + xv.w*w3.z;
                ac[r][3] += xv.x*w0.w + xv.y*w1.w + xv.z*w2.w + xv.w*w3.w;
            }
        }
        __syncthreads();                       // all reads of old s_x done

        if (tid < RPB*32){                     // stage u(t)
            int r = tid >> 5, ii = tid & 31;
            s_xc[r][128+ii] = ext[(t*1024 + r0 + r)*32 + ii];
        }
        #pragma unroll
        for (int r=0;r<RPB;r++){               // LSTM cell; c stays in registers
            float ig = sigm(ac[r][0]);
            float fg = sigm(ac[r][1]);
            float gg = tanhf_fast(ac[r][2]);
            float og = sigm(ac[r][3]);
            float c  = fg*c_reg[r] + ig*gg;
            c_reg[r] = c;
            s_x[r][128+tid] = og*tanhf_fast(c);
        }
        __syncthreads();                       // new h visible

        {   // wl logits: (r,n,part) = 4 x 8 x 8
            int r = tid >> 6, n = (tid >> 3) & 7, part = tid & 7;
            const float* wrow = wl_W + n*256 + part*32;
            const float* hrow = &s_x[r][128 + part*32];
            float p = 0.0f;
            #pragma unroll
            for (int ii=0; ii<32; ii++) p += hrow[ii]*wrow[ii];
            p += __shfl_xor(p, 1);
            p += __shfl_xor(p, 2);
            p += __shfl_xor(p, 4);
            if (part == 0) s_wlog[r][n] = p + wl_b[n];
        }
        __syncthreads();                       // logits visible

        if (tid < RPB){                        // softmax over NL=8, serial per row
            float mx = -1e30f;
            #pragma unroll
            for (int n=0;n<8;n++) mx = fmaxf(mx, s_wlog[tid][n]);
            float e[8]; float sum = 0.0f;
            #pragma unroll
            for (int n=0;n<8;n++){ e[n] = __expf(s_wlog[tid][n]-mx); sum += e[n]; }
            float inv = 1.0f/sum;
            #pragma unroll
            for (int n=0;n<8;n++) s_w[tid][n] = e[n]*inv;
        }

        // mus GEMV over [old state | u] (K=160), cols = s*8+n
        float am[RPB][4];
        #pragma unroll
        for (int r=0;r<RPB;r++){ am[r][0]=lb4.x; am[r][1]=lb4.y; am[r][2]=lb4.z; am[r][3]=lb4.w; }
        for (int i4=0;i4<40;i4++){
            float4 w0 = Ln4[(4*i4+0)*256];
            float4 w1 = Ln4[(4*i4+1)*256];
            float4 w2 = Ln4[(4*i4+2)*256];
            float4 w3 = Ln4[(4*i4+3)*256];
            #pragma unroll
            for (int r=0;r<RPB;r++){
                float4 xv = ((const float4*)s_xc[r])[i4];
                am[r][0] += xv.x*w0.x + xv.y*w1.x + xv.z*w2.x + xv.w*w3.x;
                am[r][1] += xv.x*w0.y + xv.y*w1.y + xv.z*w2.y + xv.w*w3.y;
                am[r][2] += xv.x*w0.z + xv.y*w1.z + xv.z*w2.z + xv.w*w3.z;
                am[r][3] += xv.x*w0.w + xv.y*w1.w + xv.z*w2.w + xv.w*w3.w;
            }
        }
        __syncthreads();                       // s_w visible; s_xc reads done

        {   // weighted combine across NL (lane pair) + state resample
            int sidx = tid >> 1, n0 = (tid & 1)*4;
            float stn[RPB];
            #pragma unroll
            for (int r=0;r<RPB;r++){
                float p = am[r][0]*s_w[r][n0+0] + am[r][1]*s_w[r][n0+1]
                        + am[r][2]*s_w[r][n0+2] + am[r][3]*s_w[r][n0+3];
                p += __shfl_xor(p, 1);
                stn[r] = p + s_dstd[sidx]*eps_seq[(t*1024 + r0 + r)*128 + sidx];
            }
            if ((tid & 1) == 0){
                #pragma unroll
                for (int r=0;r<RPB;r++){ s_x[r][sidx] = stn[r]; s_xc[r][sidx] = stn[r]; }
            }
        }
        if (tid < RPB*8){
            int r = tid >> 3, n = tid & 7;
            out[OUT_WMAP + (t*1024 + r0 + r)*8 + n] = s_w[r][n];
        }
        __syncthreads();                       // new state visible

        {   // fused emission: obs_mu / obs_sample
            int r = tid >> 6, o = tid & 63;
            float a = s_eb[o];
            #pragma unroll 4
            for (int s=0;s<128;s++) a += s_x[r][s]*s_HT[s][o];
            int base = (t*1024 + r0 + r)*64 + o;
            out[OUT_OBS_MU + base] = a;
            out[OUT_OBS_S  + base] = a + s_ostd[o]*eps_obs[base];
        }
    }
    #pragma unroll
    for (int r=0;r<RPB;r++){
        out[OUT_WH + (r0+r)*256 + tid] = s_x[r][128+tid];
        out[OUT_WC + (r0+r)*256 + tid] = c_reg[r];
    }
}

// ---------------- scan 2: fused PreProcess MLP + posterior LSTM ----------------
__global__ __launch_bounds__(256) void scan2_kernel(
    const float* __restrict__ ext,
    const float* __restrict__ pp_b1, const float* __restrict__ pp_b2,
    const float* __restrict__ posterior_h0,
    const float* __restrict__ ws, float* __restrict__ out)
{
    const int tid = threadIdx.x;
    const int r0  = blockIdx.x * RPB;
    __shared__ __align__(16) float s_v[RPB][512];   // [px(256) | h(256)]
    __shared__ __align__(16) float s_ax[RPB][96];
    __shared__ __align__(16) float s_l1[RPB][256];

    float c_reg[RPB];
    #pragma unroll
    for (int r=0;r<RPB;r++) c_reg[r] = 0.0f;
    {
        float h0v = posterior_h0[tid];
        #pragma unroll
        for (int r=0;r<RPB;r++) s_v[r][256+tid] = h0v;
    }
    const float4* Rn4 = ((const float4*)(ws + WS_RNNT)) + tid;
    const float4  br4 = ((const float4*)(ws + WS_BRNN))[tid];
    const float* T1 = ws + WS_PPT1;
    const float* T2 = ws + WS_PPT2;
    const float b1v = pp_b1[tid];
    const float b2v = pp_b2[tid];
    const float* obs_s = out + OUT_OBS_S;
    __syncthreads();

    for (int t = 0; t < 256; t++){
        for (int idx = tid; idx < RPB*96; idx += 256){
            int r = idx/96, i = idx - r*96;
            int row = t*1024 + r0 + r;
            s_ax[r][i] = (i < 32) ? ext[row*32 + i] : obs_s[row*64 + (i-32)];
        }
        __syncthreads();
        // MLP layer 1 (K=96)
        float l1[RPB];
        #pragma unroll
        for (int r=0;r<RPB;r++) l1[r] = b1v;
        for (int i4=0;i4<24;i4++){
            float w0 = T1[(4*i4+0)*256+tid];
            float w1 = T1[(4*i4+1)*256+tid];
            float w2 = T1[(4*i4+2)*256+tid];
            float w3 = T1[(4*i4+3)*256+tid];
            #pragma unroll
            for (int r=0;r<RPB;r++){
                float4 xv = ((const float4*)s_ax[r])[i4];
                l1[r] += xv.x*w0 + xv.y*w1 + xv.z*w2 + xv.w*w3;
            }
        }
        #pragma unroll
        for (int r=0;r<RPB;r++) s_l1[r][tid] = fmaxf(l1[r], 0.0f);
        __syncthreads();
        // MLP layer 2 -> px (K=256)
        float l2[RPB];
        #pragma unroll
        for (int r=0;r<RPB;r++) l2[r] = b2v;
        for (int i4=0;i4<64;i4++){
            float w0 = T2[(4*i4+0)*256+tid];
            float w1 = T2[(4*i4+1)*256+tid];
            float w2 = T2[(4*i4+2)*256+tid];
            float w3 = T2[(4*i4+3)*256+tid];
            #pragma unroll
            for (int r=0;r<RPB;r++){
                float4 xv = ((const float4*)s_l1[r])[i4];
                l2[r] += xv.x*w0 + xv.y*w1 + xv.z*w2 + xv.w*w3;
            }
        }
        #pragma unroll
        for (int r=0;r<RPB;r++) s_v[r][tid] = fmaxf(l2[r], 0.0f);
        __syncthreads();
        // rnn gates GEMV over [px|h] (K=512)
        float ac[RPB][4];
        #pragma unroll
        for (int r=0;r<RPB;r++){ ac[r][0]=br4.x; ac[r][1]=br4.y; ac[r][2]=br4.z; ac[r][3]=br4.w; }
        for (int i4=0;i4<128;i4++){
            float4 w0 = Rn4[(4*i4+0)*256];
            float4 w1 = Rn4[(4*i4+1)*256];
            float4 w2 = Rn4[(4*i4+2)*256];
            float4 w3 = Rn4[(4*i4+3)*256];
            #pragma unroll
            for (int r=0;r<RPB;r++){
                float4 xv = ((const float4*)s_v[r])[i4];
                ac[r][0] += xv.x*w0.x + xv.y*w1.x + xv.z*w2.x + xv.w*w3.x;
                ac[r][1] += xv.x*w0.y + xv.y*w1.y + xv.z*w2.y + xv.w*w3.y;
                ac[r][2] += xv.x*w0.z + xv.y*w1.z + xv.z*w2.z + xv.w*w3.z;
                ac[r][3] += xv.x*w0.w + xv.y*w1.w + xv.z*w2.w + xv.w*w3.w;
            }
        }
        __syncthreads();                      // all s_v reads done
        #pragma unroll
        for (int r=0;r<RPB;r++){
            float ig = sigm(ac[r][0]);
            float fg = sigm(ac[r][1]);
            float gg = tanhf_fast(ac[r][2]);
            float og = sigm(ac[r][3]);
            float c  = fg*c_reg[r] + ig*gg;
            c_reg[r] = c;
            s_v[r][256+tid] = og*tanhf_fast(c);
        }
    }
    #pragma unroll
    for (int r=0;r<RPB;r++){
        out[OUT_HPOST + (r0+r)*256 + tid] = s_v[r][256+tid];
        out[OUT_CPOST + (r0+r)*256 + tid] = c_reg[r];
    }
}

extern "C" void kernel_launch(void* const* d_in, const int* in_sizes, int n_in,
                              void* d_out, int out_size, void* d_ws, size_t ws_size,
                              hipStream_t stream) {
    const float* ext          = (const float*)d_in[0];
    const float* eps_init     = (const float*)d_in[1];
    const float* eps_seq      = (const float*)d_in[2];
    const float* eps_obs      = (const float*)d_in[3];
    const float* pp_W1        = (const float*)d_in[4];
    const float* pp_b1        = (const float*)d_in[5];
    const float* pp_W2        = (const float*)d_in[6];
    const float* pp_b2        = (const float*)d_in[7];
    const float* rnn_Wih      = (const float*)d_in[8];
    const float* rnn_Whh      = (const float*)d_in[9];
    const float* rnn_bih      = (const float*)d_in[10];
    const float* rnn_bhh      = (const float*)d_in[11];
    const float* posterior_h0 = (const float*)d_in[12];
    const float* gd_W1        = (const float*)d_in[13];
    const float* gd_b1        = (const float*)d_in[14];
    const float* gd_W2        = (const float*)d_in[15];
    const float* gd_b2        = (const float*)d_in[16];
    const float* gd_Wmu       = (const float*)d_in[17];
    const float* gd_bmu       = (const float*)d_in[18];
    const float* gd_Wls       = (const float*)d_in[19];
    const float* gd_bls       = (const float*)d_in[20];
    const float* dyn_h0       = (const float*)d_in[21];
    const float* wlstm_Wih    = (const float*)d_in[22];
    const float* wlstm_Whh    = (const float*)d_in[23];
    const float* wlstm_bih    = (const float*)d_in[24];
    const float* wlstm_bhh    = (const float*)d_in[25];
    const float* wl_W         = (const float*)d_in[26];
    const float* wl_b         = (const float*)d_in[27];
    const float* lin_W        = (const float*)d_in[28];
    const float* lin_b        = (const float*)d_in[29];
    const float* dyn_logsigma = (const float*)d_in[30];
    const float* est_logdelta = (const float*)d_in[31];
    const float* est_H        = (const float*)d_in[32];
    const float* est_bias     = (const float*)d_in[33];
    float* out = (float*)d_out;
    float* ws  = (float*)d_ws;

    prep_wcat<<<1536, 256, 0, stream>>>(wlstm_Wih, wlstm_Whh, ws);
    prep_lin <<<640,  256, 0, stream>>>(lin_W, ws);
    prep_rnn <<<2048, 256, 0, stream>>>(rnn_Wih, rnn_Whh, ws);
    prep_bias<<<4,    256, 0, stream>>>(wlstm_bih, wlstm_bhh, rnn_bih, rnn_bhh, lin_b, ws);
    prep_pp  <<<352,  256, 0, stream>>>(pp_W1, pp_W2, ws);
    dblock0  <<<1,    512, 0, stream>>>(posterior_h0, gd_W1, gd_b1, gd_W2, gd_b2,
                                        gd_Wmu, gd_bmu, gd_Wls, gd_bls, ws);
    scan1_kernel<<<256, 256, 0, stream>>>(ext, eps_init, eps_seq, eps_obs, dyn_h0,
                                          wl_W, wl_b, dyn_logsigma, est_logdelta,
                                          est_H, est_bias, ws, out);
    scan2_kernel<<<256, 256, 0, stream>>>(ext, pp_b1, pp_b2, posterior_h0, ws, out);
}